// Round 1
// baseline (136.768 us; speedup 1.0000x reference)
//
#include <hip/hip_runtime.h>
#include <hip/hip_bf16.h>
#include <math.h>

#define N_TOTAL 8192
#define D_DIM   256
#define INV_T   10.0f

typedef __bf16 bf16_8 __attribute__((ext_vector_type(8)));
typedef float  f32x4  __attribute__((ext_vector_type(4)));

#define BM 128
#define BN 128
#define BK 32
#define LDS_STRIDE (BK + 8)   // 40 bf16 = 80 B rows: 16B-aligned, 20-bank stride -> 2-way (free)

// RNE float -> bf16 (no NaN inputs here)
__device__ __forceinline__ unsigned short f2bf(float f) {
    unsigned int u = __float_as_uint(f);
    return (unsigned short)((u + 0x7FFFu + ((u >> 16) & 1u)) >> 16);
}

// Kernel 1: per-row L2 normalize concat(q,k) -> bf16 F[8192][256]
__global__ __launch_bounds__(256) void normalize_kernel(
    const float* __restrict__ q, const float* __restrict__ k,
    unsigned short* __restrict__ F)
{
    int row  = blockIdx.x * 4 + (threadIdx.x >> 6);
    int lane = threadIdx.x & 63;
    const float* src = (row < 4096) ? (q + (size_t)row * D_DIM)
                                    : (k + (size_t)(row - 4096) * D_DIM);
    float4 v = ((const float4*)src)[lane];
    float ss = v.x*v.x + v.y*v.y + v.z*v.z + v.w*v.w;
    #pragma unroll
    for (int off = 32; off > 0; off >>= 1) ss += __shfl_xor(ss, off, 64);
    float inv = 1.0f / fmaxf(sqrtf(ss), 1e-12f);
    ushort4 o;
    o.x = f2bf(v.x * inv); o.y = f2bf(v.y * inv);
    o.z = f2bf(v.z * inv); o.w = f2bf(v.w * inv);
    ((ushort4*)(F + (size_t)row * D_DIM))[lane] = o;
}

// Kernel 2: tiled F*F^T with fused exp/exclusion epilogue.
// S[i] += sum_j!=i exp(10*sim(i,j)) ; pos[i] = sim(i, (i+4096)&8191)
__global__ __launch_bounds__(256) void simloss_gemm(
    const __hip_bfloat16* __restrict__ F,
    float* __restrict__ S, float* __restrict__ pos)
{
    __shared__ __hip_bfloat16 As[BM * LDS_STRIDE];
    __shared__ __hip_bfloat16 Bs[BN * LDS_STRIDE];

    const int i0 = blockIdx.x * BM;
    const int j0 = blockIdx.y * BN;
    const int tid  = threadIdx.x;
    const int wave = tid >> 6;
    const int lane = tid & 63;
    const int wm = (wave & 1) * 64;   // wave's row quadrant
    const int wn = (wave >> 1) * 64;  // wave's col quadrant

    f32x4 acc[4][4];
    #pragma unroll
    for (int a = 0; a < 4; ++a)
        #pragma unroll
        for (int b = 0; b < 4; ++b)
            acc[a][b] = (f32x4){0.f, 0.f, 0.f, 0.f};

    const int fr = lane & 15;        // row within 16-tile (A/B operand m/n index)
    const int fk = (lane >> 4) * 8;  // k offset within 32-chunk

    for (int kk = 0; kk < D_DIM; kk += BK) {
        // stage A(128x32) and B(128x32): 512 16B-chunks each, 256 threads x 2
        #pragma unroll
        for (int c = 0; c < 2; ++c) {
            int idx = tid + c * 256;       // 0..511
            int r   = idx >> 2;            // row 0..127
            int ck  = (idx & 3) * 8;       // k element offset 0/8/16/24
            uint4 av = *(const uint4*)(F + (size_t)(i0 + r) * D_DIM + kk + ck);
            *(uint4*)(&As[r * LDS_STRIDE + ck]) = av;
            uint4 bv = *(const uint4*)(F + (size_t)(j0 + r) * D_DIM + kk + ck);
            *(uint4*)(&Bs[r * LDS_STRIDE + ck]) = bv;
        }
        __syncthreads();

        bf16_8 a[4], b[4];
        #pragma unroll
        for (int t = 0; t < 4; ++t) {
            a[t] = *(const bf16_8*)(&As[(wm + t * 16 + fr) * LDS_STRIDE + fk]);
            b[t] = *(const bf16_8*)(&Bs[(wn + t * 16 + fr) * LDS_STRIDE + fk]);
        }
        #pragma unroll
        for (int ti = 0; ti < 4; ++ti)
            #pragma unroll
            for (int tj = 0; tj < 4; ++tj)
                acc[ti][tj] = __builtin_amdgcn_mfma_f32_16x16x32_bf16(
                    a[ti], b[tj], acc[ti][tj], 0, 0, 0);
        __syncthreads();
    }

    // Epilogue. C/D layout: col = lane&15, row = (lane>>4)*4 + reg  [m89/m91 verified]
    const int g = lane >> 4;
    #pragma unroll
    for (int ti = 0; ti < 4; ++ti) {
        #pragma unroll
        for (int r = 0; r < 4; ++r) {
            const int i = i0 + wm + ti * 16 + g * 4 + r;
            const int partner = (i + 4096) & (N_TOTAL - 1);
            float esum = 0.f;
            #pragma unroll
            for (int tj = 0; tj < 4; ++tj) {
                const int j = j0 + wn + tj * 16 + (lane & 15);
                const float v = acc[ti][tj][r];
                float e = __expf(v * INV_T);
                if (j == i) e = 0.f;           // exclude diagonal
                if (j == partner) pos[i] = v;  // record positive logit (pre /T)
                esum += e;
            }
            // reduce across the 16 lanes sharing this row (low 4 lane bits)
            #pragma unroll
            for (int off = 1; off < 16; off <<= 1)
                esum += __shfl_xor(esum, off, 64);
            if ((lane & 15) == 0) atomicAdd(&S[i], esum);
        }
    }
}

// Kernel 3: loss = mean_i( log(S_i) - 10*pos_i )
__global__ __launch_bounds__(256) void finalize_kernel(
    const float* __restrict__ S, const float* __restrict__ pos,
    float* __restrict__ out)
{
    float acc = 0.f;
    for (int i = threadIdx.x; i < N_TOTAL; i += 256)
        acc += logf(S[i]) - pos[i] * INV_T;
    #pragma unroll
    for (int off = 32; off > 0; off >>= 1) acc += __shfl_xor(acc, off, 64);
    __shared__ float wsum[4];
    if ((threadIdx.x & 63) == 0) wsum[threadIdx.x >> 6] = acc;
    __syncthreads();
    if (threadIdx.x == 0)
        out[0] = (wsum[0] + wsum[1] + wsum[2] + wsum[3]) * (1.0f / N_TOTAL);
}

extern "C" void kernel_launch(void* const* d_in, const int* in_sizes, int n_in,
                              void* d_out, int out_size, void* d_ws, size_t ws_size,
                              hipStream_t stream) {
    const float* q = (const float*)d_in[0];
    const float* k = (const float*)d_in[1];
    float* out = (float*)d_out;

    char* ws = (char*)d_ws;
    const size_t f_bytes = (size_t)N_TOTAL * D_DIM * sizeof(unsigned short); // 4 MB
    unsigned short* F = (unsigned short*)ws;
    float* S   = (float*)(ws + f_bytes);
    float* pos = (float*)(ws + f_bytes + N_TOTAL * sizeof(float));

    hipMemsetAsync(S, 0, N_TOTAL * sizeof(float), stream);  // d_ws is poisoned each call
    normalize_kernel<<<N_TOTAL / 4, 256, 0, stream>>>(q, k, F);
    dim3 grid(N_TOTAL / BM, N_TOTAL / BN);  // 64 x 64
    simloss_gemm<<<grid, 256, 0, stream>>>((const __hip_bfloat16*)F, S, pos);
    finalize_kernel<<<1, 256, 0, stream>>>(S, pos, out);
}

// Round 2
// 132.799 us; speedup vs baseline: 1.0299x; 1.0299x over previous
//
#include <hip/hip_runtime.h>
#include <hip/hip_bf16.h>
#include <math.h>

#define N_TOTAL 8192
#define D_DIM   256
#define INV_T   10.0f
#define BM 128
#define BN 128
#define BK 32
#define NT 64          // 8192/128 tiles per dim; triangular grid = NT*(NT+1)/2 = 2080

typedef __bf16 bf16_8 __attribute__((ext_vector_type(8)));
typedef float  f32x4  __attribute__((ext_vector_type(4)));

typedef const __attribute__((address_space(1))) unsigned int* gptr_t;
typedef __attribute__((address_space(3))) unsigned int*       lptr_t;

// async global->LDS, 16B per lane; LDS dest = wave-uniform base + lane*16 [m97/m104]
__device__ __forceinline__ void gload16(const void* g, void* l) {
    __builtin_amdgcn_global_load_lds((gptr_t)g, (lptr_t)l, 16, 0, 0);
}

__device__ __forceinline__ unsigned short f2bf(float f) {
    unsigned int u = __float_as_uint(f);
    return (unsigned short)((u + 0x7FFFu + ((u >> 16) & 1u)) >> 16);
}

// Kernel 1: L2-normalize concat(q,k) -> bf16 F[8192][256]; also zero S.
__global__ __launch_bounds__(256) void normalize_kernel(
    const float* __restrict__ q, const float* __restrict__ k,
    unsigned short* __restrict__ F, float* __restrict__ S)
{
    if (threadIdx.x < 4) S[blockIdx.x * 4 + threadIdx.x] = 0.f;
    int row  = blockIdx.x * 4 + (threadIdx.x >> 6);
    int lane = threadIdx.x & 63;
    const float* src = (row < 4096) ? (q + (size_t)row * D_DIM)
                                    : (k + (size_t)(row - 4096) * D_DIM);
    float4 v = ((const float4*)src)[lane];
    float ss = v.x*v.x + v.y*v.y + v.z*v.z + v.w*v.w;
    #pragma unroll
    for (int off = 32; off > 0; off >>= 1) ss += __shfl_xor(ss, off, 64);
    float inv = 1.0f / fmaxf(sqrtf(ss), 1e-12f);
    ushort4 o;
    o.x = f2bf(v.x * inv); o.y = f2bf(v.y * inv);
    o.z = f2bf(v.z * inv); o.w = f2bf(v.w * inv);
    ((ushort4*)(F + (size_t)row * D_DIM))[lane] = o;
}

__device__ __forceinline__ int tri_off(int x) { return x * NT - (x * (x - 1)) / 2; }

// Kernel 2: upper-triangular tiled F*F^T with fused exp epilogue.
// Off-diag tiles feed both S[i] (row sums) and S[j] (col sums) by symmetry.
__global__ __launch_bounds__(256) void simloss_gemm(
    const __hip_bfloat16* __restrict__ F,
    float* __restrict__ S, float* __restrict__ pos)
{
    // LDS layout: chunk index (kgroup*128 + row), 8 bf16 (16 B) per chunk.
    __shared__ __hip_bfloat16 As[BM * BK];   // 8 KB
    __shared__ __hip_bfloat16 Bs[BN * BK];   // 8 KB

    // invert linear block id -> (bx, by), bx <= by
    int b  = blockIdx.x;
    int bx = (int)(64.5f - sqrtf(64.5f * 64.5f - 2.0f * (float)b));
    if (bx < 0) bx = 0; if (bx > NT - 1) bx = NT - 1;
    while (bx > 0 && tri_off(bx) > b) --bx;
    while (bx < NT - 1 && tri_off(bx + 1) <= b) ++bx;
    const int by = bx + (b - tri_off(bx));
    const bool is_diag = (bx == by);

    const int i0 = bx * BM;
    const int j0 = by * BN;
    const int tid  = threadIdx.x;
    const int wave = tid >> 6;
    const int lane = tid & 63;
    const int wm = (wave & 1) * 64;
    const int wn = (wave >> 1) * 64;
    const int g  = lane >> 4;
    const int cj = lane & 15;

    f32x4 acc[4][4];
    #pragma unroll
    for (int a = 0; a < 4; ++a)
        #pragma unroll
        for (int c = 0; c < 4; ++c)
            acc[a][c] = (f32x4){0.f, 0.f, 0.f, 0.f};

    for (int kk = 0; kk < D_DIM; kk += BK) {
        // wave w stages k-group w (8 bf16 = 16 B) for rows p*64+lane.
        // LDS chunk c = w*128 + p*64 + lane  ==  (kgroup=w)*128 + (row=p*64+lane). ✓
        #pragma unroll
        for (int p = 0; p < 2; ++p) {
            gload16(F + (size_t)(i0 + p * 64 + lane) * D_DIM + kk + wave * 8,
                    &As[(wave * 128 + p * 64) * 8]);
            gload16(F + (size_t)(j0 + p * 64 + lane) * D_DIM + kk + wave * 8,
                    &Bs[(wave * 128 + p * 64) * 8]);
        }
        __syncthreads();

        bf16_8 a[4], bfr[4];
        #pragma unroll
        for (int t = 0; t < 4; ++t) {
            a[t]   = *(const bf16_8*)(&As[(g * 128 + wm + t * 16 + cj) * 8]);
            bfr[t] = *(const bf16_8*)(&Bs[(g * 128 + wn + t * 16 + cj) * 8]);
        }
        #pragma unroll
        for (int ti = 0; ti < 4; ++ti)
            #pragma unroll
            for (int tj = 0; tj < 4; ++tj)
                acc[ti][tj] = __builtin_amdgcn_mfma_f32_16x16x32_bf16(
                    a[ti], bfr[tj], acc[ti][tj], 0, 0, 0);
        __syncthreads();
    }

    // Epilogue. C/D layout: col = lane&15, row = (lane>>4)*4 + reg [m89/m91]
    float colsum[4] = {0.f, 0.f, 0.f, 0.f};
    #pragma unroll
    for (int ti = 0; ti < 4; ++ti) {
        #pragma unroll
        for (int r = 0; r < 4; ++r) {
            const int i = i0 + wm + ti * 16 + g * 4 + r;
            const int partner = (i + 4096) & (N_TOTAL - 1);
            float esum = 0.f;
            #pragma unroll
            for (int tj = 0; tj < 4; ++tj) {
                const int j = j0 + wn + tj * 16 + cj;
                const float v = acc[ti][tj][r];
                float e = __expf(v * INV_T);
                if (is_diag && j == i) e = 0.f;               // exclude diagonal
                if (!is_diag && j == partner) {               // mutual positives
                    pos[i] = v; pos[j] = v;
                }
                esum += e;
                colsum[tj] += e;
            }
            #pragma unroll
            for (int off = 1; off < 16; off <<= 1)
                esum += __shfl_xor(esum, off, 64);
            if (cj == 0) atomicAdd(&S[i], esum);
        }
    }
    if (!is_diag) {
        #pragma unroll
        for (int tj = 0; tj < 4; ++tj) {
            float cs = colsum[tj];
            cs += __shfl_xor(cs, 16, 64);
            cs += __shfl_xor(cs, 32, 64);
            if (g == 0) atomicAdd(&S[j0 + wn + tj * 16 + cj], cs);
        }
    }
}

// Kernel 3: loss = mean_i( log(S_i) - 10*pos_i )
__global__ __launch_bounds__(256) void finalize_kernel(
    const float* __restrict__ S, const float* __restrict__ pos,
    float* __restrict__ out)
{
    float acc = 0.f;
    for (int i = threadIdx.x; i < N_TOTAL; i += 256)
        acc += logf(S[i]) - pos[i] * INV_T;
    #pragma unroll
    for (int off = 32; off > 0; off >>= 1) acc += __shfl_xor(acc, off, 64);
    __shared__ float wsum[4];
    if ((threadIdx.x & 63) == 0) wsum[threadIdx.x >> 6] = acc;
    __syncthreads();
    if (threadIdx.x == 0)
        out[0] = (wsum[0] + wsum[1] + wsum[2] + wsum[3]) * (1.0f / N_TOTAL);
}

extern "C" void kernel_launch(void* const* d_in, const int* in_sizes, int n_in,
                              void* d_out, int out_size, void* d_ws, size_t ws_size,
                              hipStream_t stream) {
    const float* q = (const float*)d_in[0];
    const float* k = (const float*)d_in[1];
    float* out = (float*)d_out;

    char* ws = (char*)d_ws;
    const size_t f_bytes = (size_t)N_TOTAL * D_DIM * sizeof(unsigned short); // 4 MB
    unsigned short* F = (unsigned short*)ws;
    float* S   = (float*)(ws + f_bytes);
    float* pos = (float*)(ws + f_bytes + N_TOTAL * sizeof(float));

    normalize_kernel<<<N_TOTAL / 4, 256, 0, stream>>>(q, k, F, S);
    simloss_gemm<<<NT * (NT + 1) / 2, 256, 0, stream>>>((const __hip_bfloat16*)F, S, pos);
    finalize_kernel<<<1, 256, 0, stream>>>(S, pos, out);
}